// Round 15
// baseline (226.491 us; speedup 1.0000x reference)
//
#include <hip/hip_runtime.h>
#include <math.h>

// ---- Problem constants ----
#define B_    128
#define L_    512
#define H_    128
#define NPT_  1023
#define N_    (B_ * NPT_)     // 130944
#define NLEAF (B_ * L_)       // 65536
#define OUT_  128
#define VOCAB 32000
#define TBASE 960             // first tail node (cnt=32 level base)
#define BROW  264             // padded LDS B-row (256+8 shorts): 2-way = free

typedef unsigned short ushort_t;
typedef __attribute__((ext_vector_type(8))) __bf16 bf16x8;
typedef __attribute__((ext_vector_type(4))) float f32x4;

__device__ __forceinline__ float sigmoidf_(float x) {
    return 1.0f / (1.0f + __expf(-x));
}
__device__ __forceinline__ float tanhf_(float x) {
    return 1.0f - 2.0f / (__expf(2.0f * x) + 1.0f);
}
__device__ __forceinline__ ushort_t f2bf(float f) {
    unsigned u = __float_as_uint(f);
    return (ushort_t)((u + 0x7fffu + ((u >> 16) & 1u)) >> 16);
}
__device__ __forceinline__ float bf2f(ushort_t s) {
    return __uint_as_float(((unsigned)s) << 16);
}

// =====================================================================
// Prep (fused): weights -> bf16 transposed, emb -> bf16.
// =====================================================================
__global__ __launch_bounds__(256)
void prep_fused(const float* __restrict__ W_iou,
                const float* __restrict__ U_iou,
                const float* __restrict__ U_f_w,
                const float* __restrict__ emb,
                ushort_t* __restrict__ W_iouT,     // [384][128]
                ushort_t* __restrict__ U_catT,     // [640][256]
                ushort_t* __restrict__ embb) {     // [VOCAB][128]
    int idx = blockIdx.x * 256 + threadIdx.x;
    if (idx < VOCAB * H_ / 8) {
        int e0 = idx * 8;
        f32x4 f0 = *(const f32x4*)(emb + e0);
        f32x4 f1 = *(const f32x4*)(emb + e0 + 4);
        union { bf16x8 v; ushort_t e[8]; } p;
        p.e[0] = f2bf(f0[0]); p.e[1] = f2bf(f0[1]);
        p.e[2] = f2bf(f0[2]); p.e[3] = f2bf(f0[3]);
        p.e[4] = f2bf(f1[0]); p.e[5] = f2bf(f1[1]);
        p.e[6] = f2bf(f1[2]); p.e[7] = f2bf(f1[3]);
        *(bf16x8*)(embb + e0) = p.v;
    }
    if (idx < 640 * 256) {
        int n = idx >> 8, k = idx & 255;
        float v = (n < 384) ? U_iou[k * 384 + n] : U_f_w[k * 256 + (n - 384)];
        U_catT[idx] = f2bf(v);
    }
    if (idx < 384 * 128) {
        int n = idx >> 7, k = idx & 127;
        W_iouT[idx] = f2bf(W_iou[k * 384 + n]);
    }
}

// =====================================================================
// Leaf (B register-resident, labels preloaded) — r13 shape; c bf16.
// =====================================================================
__global__ __launch_bounds__(256, 4)
void leaf_v3(const int* __restrict__ label,
             const ushort_t* __restrict__ embb,
             const ushort_t* __restrict__ WT,
             const float* __restrict__ b_iou,
             ushort_t* __restrict__ h,
             ushort_t* __restrict__ c) {
    const int tid  = threadIdx.x;
    const int lane = tid & 63;
    const int wave = tid >> 6;
    const int li   = lane & 15;
    const int q    = lane >> 4;
    const int q8   = q << 3;
    const int gg   = blockIdx.y * 4 + wave;
    const int j    = gg * 16 + li;

    bf16x8 Bf[3][4];
    #pragma unroll
    for (int t = 0; t < 3; ++t) {
        const ushort_t* bp = WT + (size_t)(16 * (gg + 8 * t) + li) * 128 + q8;
        #pragma unroll
        for (int kt = 0; kt < 4; ++kt) Bf[t][kt] = *(const bf16x8*)(bp + kt * 32);
    }

    int lab[8];
    #pragma unroll
    for (int t = 0; t < 8; ++t) {
        int ia = (blockIdx.x + t * 512) * 16 + li;
        int ba = ia >> 9, pa = ia & 511;
        lab[t] = label[ba * NPT_ + pa];
    }

    const float bi = b_iou[j], bo = b_iou[128 + j], bu = b_iou[256 + j];

    #pragma unroll 1
    for (int t8 = 0; t8 < 8; ++t8) {
        const int tile = blockIdx.x + t8 * 512;
        const int i0 = tile * 16;
        const ushort_t* pA = embb + (size_t)lab[t8] * H_;
        bf16x8 a[4];
        #pragma unroll
        for (int kt = 0; kt < 4; ++kt) a[kt] = *(const bf16x8*)(pA + kt * 32 + q8);

        f32x4 acc[3];
        #pragma unroll
        for (int t = 0; t < 3; ++t) acc[t] = (f32x4){0.f, 0.f, 0.f, 0.f};
        #pragma unroll
        for (int kt = 0; kt < 4; ++kt)
            #pragma unroll
            for (int t = 0; t < 3; ++t)
                acc[t] = __builtin_amdgcn_mfma_f32_16x16x32_bf16(a[kt], Bf[t][kt], acc[t], 0, 0, 0);

        #pragma unroll
        for (int r = 0; r < 4; ++r) {
            int m  = i0 + q * 4 + r;
            int b  = m >> 9, pos = m & 511;
            size_t gn = (size_t)(b * NPT_ + pos) * H_ + j;
            float iv = sigmoidf_(acc[0][r] + bi);
            float ov = sigmoidf_(acc[1][r] + bo);
            float uv = tanhf_(acc[2][r] + bu);
            float cv = iv * uv;
            float hv = ov * tanhf_(cv);
            c[gn] = f2bf(cv);
            h[gn] = f2bf(hv);
        }
    }
}

// =====================================================================
// Level, B in LDS, M=16/wave — exact r13 shape (verified fast); c bf16.
// Block = 4 waves, ONE gate group (blockIdx.y); B slice staged to LDS
// once (one barrier); waves independently run M-tiles of 16.
// =====================================================================
__global__ __launch_bounds__(256, 2)
void level_lds(const ushort_t* __restrict__ Ucat,
               const float* __restrict__ b_iou,
               const float* __restrict__ U_f_b,
               ushort_t* __restrict__ h,
               ushort_t* __restrict__ c,
               int node_base, int child_base, int lc, int ntiles) {
    __shared__ ushort_t Bs[5 * 16 * BROW];          // 42.2 KB
    const int tid  = threadIdx.x;
    const int lane = tid & 63;
    const int wave = tid >> 6;
    const int li   = lane & 15;
    const int q    = lane >> 4;
    const int q8   = q << 3;
    const int mask = (1 << lc) - 1;
    const int gg   = blockIdx.y;                    // gate group
    const int j    = gg * 16 + li;

    // ---- stage B: 80 rows x 256 shorts, coalesced 32B chunks ----
    #pragma unroll
    for (int it = 0; it < 5; ++it) {
        int chunk = tid + it * 256;                 // 0..1279
        int row = chunk >> 4, seg = chunk & 15;
        int t = row >> 4, lr = row & 15;
        const ushort_t* src = Ucat + (size_t)(16 * (gg + 8 * t) + lr) * 256 + seg * 16;
        ushort_t*       dst = Bs + (t * 16 + lr) * BROW + seg * 16;
        *(f32x4*)(dst)     = *(const f32x4*)(src);
        *(f32x4*)(dst + 8) = *(const f32x4*)(src + 8);
    }
    __syncthreads();

    const float bi  = b_iou[j], bo = b_iou[128 + j], bu = b_iou[256 + j];
    const float bfl = U_f_b[j], bfr = U_f_b[128 + j];
    const int wstride = gridDim.x * 4;

    #pragma unroll 1
    for (int tile = blockIdx.x * 4 + wave; tile < ntiles; tile += wstride) {
        const int i0 = tile * 16;

        // epilogue c-children prefetch (independent; hides under K-loop)
        float clv[4], crv[4];
        int   gnrow[4];
        #pragma unroll
        for (int r = 0; r < 4; ++r) {
            int m = i0 + q * 4 + r;
            int b = m >> lc, pos = m & mask;
            int gl = b * NPT_ + child_base + 2 * pos;
            gnrow[r] = b * NPT_ + node_base + pos;
            clv[r] = bf2f(c[(size_t)gl * H_ + j]);
            crv[r] = bf2f(c[(size_t)(gl + 1) * H_ + j]);
        }

        // A: 16 h_cat rows; kt<4 left child, kt>=4 right child
        int ia = i0 + li, ba = ia >> lc, pa = ia & mask;
        int gl0 = ba * NPT_ + child_base + 2 * pa;
        const ushort_t* pl = h + (size_t)gl0 * H_;
        const ushort_t* pr = h + (size_t)(gl0 + 1) * H_;
        bf16x8 a[8];
        #pragma unroll
        for (int kt = 0; kt < 8; ++kt) {
            const ushort_t* p = (kt < 4) ? pl : pr;
            a[kt] = *(const bf16x8*)(p + (kt & 3) * 32 + q8);
        }

        f32x4 acc[5];
        #pragma unroll
        for (int t = 0; t < 5; ++t) acc[t] = (f32x4){0.f, 0.f, 0.f, 0.f};
        #pragma unroll
        for (int kt = 0; kt < 8; ++kt) {
            #pragma unroll
            for (int t = 0; t < 5; ++t) {
                bf16x8 bf = *(const bf16x8*)(Bs + (t * 16 + li) * BROW + kt * 32 + q8);
                acc[t] = __builtin_amdgcn_mfma_f32_16x16x32_bf16(a[kt], bf, acc[t], 0, 0, 0);
            }
        }

        #pragma unroll
        for (int r = 0; r < 4; ++r) {
            size_t gn = (size_t)gnrow[r] * H_ + j;
            float iv = sigmoidf_(acc[0][r] + bi);
            float ov = sigmoidf_(acc[1][r] + bo);
            float uv = tanhf_(acc[2][r] + bu);
            float fl = sigmoidf_(acc[3][r] + bfl);
            float fr = sigmoidf_(acc[4][r] + bfr);
            float cv = iv * uv + fl * clv[r] + fr * crv[r];
            float hv = ov * tanhf_(cv);
            c[gn] = f2bf(cv);
            h[gn] = f2bf(hv);
        }
    }
}

// =====================================================================
// Tail — r12-verified shape: one block (8 waves = 8 gate groups) per
// TREE. Levels cnt=32..1 + root; tail h/c in LDS; global c reads bf16.
// =====================================================================
#define TPAD 132
__global__ __launch_bounds__(512, 2)
void tail_kernel(const ushort_t* __restrict__ Ucat,
                 const float* __restrict__ b_iou,
                 const float* __restrict__ U_f_b,
                 const ushort_t* __restrict__ h,
                 const ushort_t* __restrict__ c,
                 const float* __restrict__ W_out,
                 const float* __restrict__ b_out,
                 float* __restrict__ out) {
    __shared__ ushort_t hl[63][TPAD];
    __shared__ float    cl[63][TPAD];
    __shared__ float    ev[H_];
    __shared__ float    red[128];

    const int tid  = threadIdx.x;
    const int lane = tid & 63;
    const int wave = tid >> 6;
    const int li   = lane & 15;
    const int q    = lane >> 4;
    const int q8   = q << 3;
    const int gg   = wave;
    const int j    = gg * 16 + li;
    const int b    = blockIdx.x;

    bf16x8 Bf[5][8];
    #pragma unroll
    for (int t = 0; t < 5; ++t) {
        const ushort_t* bp = Ucat + (size_t)(16 * (gg + 8 * t) + li) * 256 + q8;
        #pragma unroll
        for (int kt = 0; kt < 8; ++kt) Bf[t][kt] = *(const bf16x8*)(bp + kt * 32);
    }

    const float bi  = b_iou[j], bo = b_iou[128 + j], bu = b_iou[256 + j];
    const float bfl = U_f_b[j], bfr = U_f_b[128 + j];

    int base = TBASE, child = 896, cnt = 32;
    #pragma unroll 1
    for (int lvl = 0; lvl < 6; ++lvl) {
        const int tiles = (cnt + 15) >> 4;
        for (int tile = 0; tile < tiles; ++tile) {
            const int i0 = tile * 16;

            int pos = i0 + li; if (pos >= cnt) pos = cnt - 1;
            bf16x8 a[8];
            if (lvl == 0) {
                int gl0 = b * NPT_ + child + 2 * pos;
                const ushort_t* pl = h + (size_t)gl0 * H_;
                const ushort_t* pr = h + (size_t)(gl0 + 1) * H_;
                #pragma unroll
                for (int kt = 0; kt < 8; ++kt) {
                    const ushort_t* p = (kt < 4) ? pl : pr;
                    a[kt] = *(const bf16x8*)(p + (kt & 3) * 32 + q8);
                }
            } else {
                int tl = (child - TBASE) + 2 * pos;
                #pragma unroll
                for (int kt = 0; kt < 8; ++kt) {
                    const ushort_t* p = (kt < 4) ? hl[tl] : hl[tl + 1];
                    a[kt] = *(const bf16x8*)(p + (kt & 3) * 32 + q8);
                }
            }

            float clv[4], crv[4];
            #pragma unroll
            for (int r = 0; r < 4; ++r) {
                int m  = i0 + q * 4 + r;
                int pm = m < cnt ? m : cnt - 1;
                if (lvl == 0) {
                    int gl = b * NPT_ + child + 2 * pm;
                    clv[r] = bf2f(c[(size_t)gl * H_ + j]);
                    crv[r] = bf2f(c[(size_t)(gl + 1) * H_ + j]);
                } else {
                    int tl = (child - TBASE) + 2 * pm;
                    clv[r] = cl[tl][j];
                    crv[r] = cl[tl + 1][j];
                }
            }

            f32x4 acc[5];
            #pragma unroll
            for (int t = 0; t < 5; ++t) acc[t] = (f32x4){0.f, 0.f, 0.f, 0.f};
            #pragma unroll
            for (int kt = 0; kt < 8; ++kt)
                #pragma unroll
                for (int t = 0; t < 5; ++t)
                    acc[t] = __builtin_amdgcn_mfma_f32_16x16x32_bf16(a[kt], Bf[t][kt], acc[t], 0, 0, 0);

            #pragma unroll
            for (int r = 0; r < 4; ++r) {
                int m = i0 + q * 4 + r;
                if (m < cnt) {
                    int tl = (base - TBASE) + m;
                    float iv = sigmoidf_(acc[0][r] + bi);
                    float ov = sigmoidf_(acc[1][r] + bo);
                    float uv = tanhf_(acc[2][r] + bu);
                    float fl = sigmoidf_(acc[3][r] + bfl);
                    float fr = sigmoidf_(acc[4][r] + bfr);
                    float cv = iv * uv + fl * clv[r] + fr * crv[r];
                    float hv = ov * tanhf_(cv);
                    cl[tl][j] = cv;
                    hl[tl][j] = f2bf(hv);
                }
            }
        }
        __syncthreads();
        child = base; base += cnt; cnt >>= 1;
    }

    if (tid < 128) ev[tid] = bf2f(hl[62][tid]);
    __syncthreads();

    float acc = 0.0f;
    if (tid < 128) {
        acc = b_out[tid];
        for (int k = 0; k < H_; ++k)
            acc += ev[k] * W_out[k * OUT_ + tid];
        red[tid] = acc;
    }
    __syncthreads();
    for (int s = 64; s > 0; s >>= 1) {
        if (tid < s) red[tid] = fmaxf(red[tid], red[tid + s]);
        __syncthreads();
    }
    float mx = red[0];
    __syncthreads();
    if (tid < 128) red[tid] = expf(acc - mx);
    __syncthreads();
    for (int s = 64; s > 0; s >>= 1) {
        if (tid < s) red[tid] += red[tid + s];
        __syncthreads();
    }
    float lse = logf(red[0]);
    if (tid < 128) out[b * OUT_ + tid] = acc - mx - lse;
}

// =====================================================================
extern "C" void kernel_launch(void* const* d_in, const int* in_sizes, int n_in,
                              void* d_out, int out_size, void* d_ws, size_t ws_size,
                              hipStream_t stream) {
    const int*   label = (const int*)d_in[0];
    const float* emb   = (const float*)d_in[1];
    const float* W_iou = (const float*)d_in[2];
    const float* U_iou = (const float*)d_in[3];
    const float* b_iou = (const float*)d_in[4];
    const float* U_f_w = (const float*)d_in[5];
    const float* U_f_b = (const float*)d_in[6];
    const float* W_out = (const float*)d_in[7];
    const float* b_out = (const float*)d_in[8];
    float* outp = (float*)d_out;

    // ws layout: c bf16 | h bf16 | Ucat | WT | embb
    ushort_t* c    = (ushort_t*)d_ws;
    ushort_t* h    = c + (size_t)N_ * H_;
    ushort_t* Ucat = h + (size_t)N_ * H_;
    ushort_t* WT   = Ucat + 640 * 256;
    ushort_t* embb = WT + 384 * 128;

    prep_fused<<<2000, 256, 0, stream>>>(W_iou, U_iou, U_f_w, emb, WT, Ucat, embb);

    // leaf: 4096 M-tiles of 16; 512 stripes x 2 group-halves; 8 tiles/wave
    leaf_v3<<<dim3(512, 2), 256, 0, stream>>>(label, embb, WT, b_iou, h, c);

    // big levels: cnt = 256,128,64 — B in LDS, M=16/wave, 4 tiles/wave
    int child = 0, node = 512, cnt = 256, lc = 8;
    for (int lvl = 0; lvl < 3; ++lvl) {
        int ntiles  = (B_ * cnt) / 16;
        int stripes = ntiles / 16;          // 4 waves x 4 tiles per block
        level_lds<<<dim3(stripes, 8), 256, 0, stream>>>(
            Ucat, b_iou, U_f_b, h, c, node, child, lc, ntiles);
        child = node; node += cnt; cnt >>= 1; --lc;
    }

    // tail: cnt=32..1 + root, one block per tree
    tail_kernel<<<B_, 512, 0, stream>>>(Ucat, b_iou, U_f_b, h, c, W_out, b_out, outp);
}

// Round 16
// 200.010 us; speedup vs baseline: 1.1324x; 1.1324x over previous
//
#include <hip/hip_runtime.h>
#include <math.h>

// ---- Problem constants ----
#define B_    128
#define L_    512
#define H_    128
#define NPT_  1023
#define N_    (B_ * NPT_)     // 130944
#define NLEAF (B_ * L_)       // 65536
#define OUT_  128
#define VOCAB 32000
#define TBASE 960             // first tail node (cnt=32 level base)
#define BROW  264             // padded LDS B-row (256+8 shorts): 2-way = free

typedef unsigned short ushort_t;
typedef __attribute__((ext_vector_type(8))) __bf16 bf16x8;
typedef __attribute__((ext_vector_type(4))) float f32x4;

__device__ __forceinline__ float sigmoidf_(float x) {
    return 1.0f / (1.0f + __expf(-x));
}
__device__ __forceinline__ float tanhf_(float x) {
    return 1.0f - 2.0f / (__expf(2.0f * x) + 1.0f);
}
__device__ __forceinline__ ushort_t f2bf(float f) {
    unsigned u = __float_as_uint(f);
    return (ushort_t)((u + 0x7fffu + ((u >> 16) & 1u)) >> 16);
}
__device__ __forceinline__ float bf2f(ushort_t s) {
    return __uint_as_float(((unsigned)s) << 16);
}

// =====================================================================
// Prep (fused): weights -> bf16 transposed, emb -> bf16.
// =====================================================================
__global__ __launch_bounds__(256)
void prep_fused(const float* __restrict__ W_iou,
                const float* __restrict__ U_iou,
                const float* __restrict__ U_f_w,
                const float* __restrict__ emb,
                ushort_t* __restrict__ W_iouT,     // [384][128]
                ushort_t* __restrict__ U_catT,     // [640][256]
                ushort_t* __restrict__ embb) {     // [VOCAB][128]
    int idx = blockIdx.x * 256 + threadIdx.x;
    if (idx < VOCAB * H_ / 8) {
        int e0 = idx * 8;
        f32x4 f0 = *(const f32x4*)(emb + e0);
        f32x4 f1 = *(const f32x4*)(emb + e0 + 4);
        union { bf16x8 v; ushort_t e[8]; } p;
        p.e[0] = f2bf(f0[0]); p.e[1] = f2bf(f0[1]);
        p.e[2] = f2bf(f0[2]); p.e[3] = f2bf(f0[3]);
        p.e[4] = f2bf(f1[0]); p.e[5] = f2bf(f1[1]);
        p.e[6] = f2bf(f1[2]); p.e[7] = f2bf(f1[3]);
        *(bf16x8*)(embb + e0) = p.v;
    }
    if (idx < 640 * 256) {
        int n = idx >> 8, k = idx & 255;
        float v = (n < 384) ? U_iou[k * 384 + n] : U_f_w[k * 256 + (n - 384)];
        U_catT[idx] = f2bf(v);
    }
    if (idx < 384 * 128) {
        int n = idx >> 7, k = idx & 127;
        W_iouT[idx] = f2bf(W_iou[k * 384 + n]);
    }
}

// =====================================================================
// Leaf (B register-resident, labels preloaded) — r13-verified; c f32.
// =====================================================================
__global__ __launch_bounds__(256, 4)
void leaf_v3(const int* __restrict__ label,
             const ushort_t* __restrict__ embb,
             const ushort_t* __restrict__ WT,
             const float* __restrict__ b_iou,
             ushort_t* __restrict__ h,
             float* __restrict__ c) {
    const int tid  = threadIdx.x;
    const int lane = tid & 63;
    const int wave = tid >> 6;
    const int li   = lane & 15;
    const int q    = lane >> 4;
    const int q8   = q << 3;
    const int gg   = blockIdx.y * 4 + wave;
    const int j    = gg * 16 + li;

    bf16x8 Bf[3][4];
    #pragma unroll
    for (int t = 0; t < 3; ++t) {
        const ushort_t* bp = WT + (size_t)(16 * (gg + 8 * t) + li) * 128 + q8;
        #pragma unroll
        for (int kt = 0; kt < 4; ++kt) Bf[t][kt] = *(const bf16x8*)(bp + kt * 32);
    }

    int lab[8];
    #pragma unroll
    for (int t = 0; t < 8; ++t) {
        int ia = (blockIdx.x + t * 512) * 16 + li;
        int ba = ia >> 9, pa = ia & 511;
        lab[t] = label[ba * NPT_ + pa];
    }

    const float bi = b_iou[j], bo = b_iou[128 + j], bu = b_iou[256 + j];

    #pragma unroll 1
    for (int t8 = 0; t8 < 8; ++t8) {
        const int tile = blockIdx.x + t8 * 512;
        const int i0 = tile * 16;
        const ushort_t* pA = embb + (size_t)lab[t8] * H_;
        bf16x8 a[4];
        #pragma unroll
        for (int kt = 0; kt < 4; ++kt) a[kt] = *(const bf16x8*)(pA + kt * 32 + q8);

        f32x4 acc[3];
        #pragma unroll
        for (int t = 0; t < 3; ++t) acc[t] = (f32x4){0.f, 0.f, 0.f, 0.f};
        #pragma unroll
        for (int kt = 0; kt < 4; ++kt)
            #pragma unroll
            for (int t = 0; t < 3; ++t)
                acc[t] = __builtin_amdgcn_mfma_f32_16x16x32_bf16(a[kt], Bf[t][kt], acc[t], 0, 0, 0);

        #pragma unroll
        for (int r = 0; r < 4; ++r) {
            int m  = i0 + q * 4 + r;
            int b  = m >> 9, pos = m & 511;
            size_t gn = (size_t)(b * NPT_ + pos) * H_ + j;
            float iv = sigmoidf_(acc[0][r] + bi);
            float ov = sigmoidf_(acc[1][r] + bo);
            float uv = tanhf_(acc[2][r] + bu);
            float cv = iv * uv;
            float hv = ov * tanhf_(cv);
            c[gn] = cv;
            h[gn] = f2bf(hv);
        }
    }
}

// =====================================================================
// Level, B in LDS, M=16/wave — r13-verified; c f32. Block = 4 waves,
// ONE gate group (blockIdx.y); B slice staged to LDS once (one
// barrier); waves independently run M-tiles of 16.
// =====================================================================
__global__ __launch_bounds__(256, 2)
void level_lds(const ushort_t* __restrict__ Ucat,
               const float* __restrict__ b_iou,
               const float* __restrict__ U_f_b,
               ushort_t* __restrict__ h,
               float* __restrict__ c,
               int node_base, int child_base, int lc, int ntiles) {
    __shared__ ushort_t Bs[5 * 16 * BROW];          // 42.2 KB
    const int tid  = threadIdx.x;
    const int lane = tid & 63;
    const int wave = tid >> 6;
    const int li   = lane & 15;
    const int q    = lane >> 4;
    const int q8   = q << 3;
    const int mask = (1 << lc) - 1;
    const int gg   = blockIdx.y;                    // gate group
    const int j    = gg * 16 + li;

    // ---- stage B: 80 rows x 256 shorts, coalesced 32B chunks ----
    #pragma unroll
    for (int it = 0; it < 5; ++it) {
        int chunk = tid + it * 256;                 // 0..1279
        int row = chunk >> 4, seg = chunk & 15;
        int t = row >> 4, lr = row & 15;
        const ushort_t* src = Ucat + (size_t)(16 * (gg + 8 * t) + lr) * 256 + seg * 16;
        ushort_t*       dst = Bs + (t * 16 + lr) * BROW + seg * 16;
        *(f32x4*)(dst)     = *(const f32x4*)(src);
        *(f32x4*)(dst + 8) = *(const f32x4*)(src + 8);
    }
    __syncthreads();

    const float bi  = b_iou[j], bo = b_iou[128 + j], bu = b_iou[256 + j];
    const float bfl = U_f_b[j], bfr = U_f_b[128 + j];
    const int wstride = gridDim.x * 4;

    #pragma unroll 1
    for (int tile = blockIdx.x * 4 + wave; tile < ntiles; tile += wstride) {
        const int i0 = tile * 16;

        // epilogue c-children prefetch (independent; hides under K-loop)
        float clv[4], crv[4];
        int   gnrow[4];
        #pragma unroll
        for (int r = 0; r < 4; ++r) {
            int m = i0 + q * 4 + r;
            int b = m >> lc, pos = m & mask;
            int gl = b * NPT_ + child_base + 2 * pos;
            gnrow[r] = b * NPT_ + node_base + pos;
            clv[r] = c[(size_t)gl * H_ + j];
            crv[r] = c[(size_t)(gl + 1) * H_ + j];
        }

        // A: 16 h_cat rows; kt<4 left child, kt>=4 right child
        int ia = i0 + li, ba = ia >> lc, pa = ia & mask;
        int gl0 = ba * NPT_ + child_base + 2 * pa;
        const ushort_t* pl = h + (size_t)gl0 * H_;
        const ushort_t* pr = h + (size_t)(gl0 + 1) * H_;
        bf16x8 a[8];
        #pragma unroll
        for (int kt = 0; kt < 8; ++kt) {
            const ushort_t* p = (kt < 4) ? pl : pr;
            a[kt] = *(const bf16x8*)(p + (kt & 3) * 32 + q8);
        }

        f32x4 acc[5];
        #pragma unroll
        for (int t = 0; t < 5; ++t) acc[t] = (f32x4){0.f, 0.f, 0.f, 0.f};
        #pragma unroll
        for (int kt = 0; kt < 8; ++kt) {
            #pragma unroll
            for (int t = 0; t < 5; ++t) {
                bf16x8 bf = *(const bf16x8*)(Bs + (t * 16 + li) * BROW + kt * 32 + q8);
                acc[t] = __builtin_amdgcn_mfma_f32_16x16x32_bf16(a[kt], bf, acc[t], 0, 0, 0);
            }
        }

        #pragma unroll
        for (int r = 0; r < 4; ++r) {
            size_t gn = (size_t)gnrow[r] * H_ + j;
            float iv = sigmoidf_(acc[0][r] + bi);
            float ov = sigmoidf_(acc[1][r] + bo);
            float uv = tanhf_(acc[2][r] + bu);
            float fl = sigmoidf_(acc[3][r] + bfl);
            float fr = sigmoidf_(acc[4][r] + bfr);
            float cv = iv * uv + fl * clv[r] + fr * crv[r];
            float hv = ov * tanhf_(cv);
            c[gn] = cv;
            h[gn] = f2bf(hv);
        }
    }
}

// =====================================================================
// Tail — r13-verified: one block (8 waves = 8 gate groups) per TREE.
// Levels cnt=32..1 + root; tail h/c in LDS (63 nodes); c f32.
// =====================================================================
#define TPAD 132
__global__ __launch_bounds__(512, 2)
void tail_kernel(const ushort_t* __restrict__ Ucat,
                 const float* __restrict__ b_iou,
                 const float* __restrict__ U_f_b,
                 const ushort_t* __restrict__ h,
                 const float* __restrict__ c,
                 const float* __restrict__ W_out,
                 const float* __restrict__ b_out,
                 float* __restrict__ out) {
    __shared__ ushort_t hl[63][TPAD];
    __shared__ float    cl[63][TPAD];
    __shared__ float    ev[H_];
    __shared__ float    red[128];

    const int tid  = threadIdx.x;
    const int lane = tid & 63;
    const int wave = tid >> 6;
    const int li   = lane & 15;
    const int q    = lane >> 4;
    const int q8   = q << 3;
    const int gg   = wave;
    const int j    = gg * 16 + li;
    const int b    = blockIdx.x;

    bf16x8 Bf[5][8];
    #pragma unroll
    for (int t = 0; t < 5; ++t) {
        const ushort_t* bp = Ucat + (size_t)(16 * (gg + 8 * t) + li) * 256 + q8;
        #pragma unroll
        for (int kt = 0; kt < 8; ++kt) Bf[t][kt] = *(const bf16x8*)(bp + kt * 32);
    }

    const float bi  = b_iou[j], bo = b_iou[128 + j], bu = b_iou[256 + j];
    const float bfl = U_f_b[j], bfr = U_f_b[128 + j];

    int base = TBASE, child = 896, cnt = 32;
    #pragma unroll 1
    for (int lvl = 0; lvl < 6; ++lvl) {
        const int tiles = (cnt + 15) >> 4;
        for (int tile = 0; tile < tiles; ++tile) {
            const int i0 = tile * 16;

            int pos = i0 + li; if (pos >= cnt) pos = cnt - 1;
            bf16x8 a[8];
            if (lvl == 0) {
                int gl0 = b * NPT_ + child + 2 * pos;
                const ushort_t* pl = h + (size_t)gl0 * H_;
                const ushort_t* pr = h + (size_t)(gl0 + 1) * H_;
                #pragma unroll
                for (int kt = 0; kt < 8; ++kt) {
                    const ushort_t* p = (kt < 4) ? pl : pr;
                    a[kt] = *(const bf16x8*)(p + (kt & 3) * 32 + q8);
                }
            } else {
                int tl = (child - TBASE) + 2 * pos;
                #pragma unroll
                for (int kt = 0; kt < 8; ++kt) {
                    const ushort_t* p = (kt < 4) ? hl[tl] : hl[tl + 1];
                    a[kt] = *(const bf16x8*)(p + (kt & 3) * 32 + q8);
                }
            }

            float clv[4], crv[4];
            #pragma unroll
            for (int r = 0; r < 4; ++r) {
                int m  = i0 + q * 4 + r;
                int pm = m < cnt ? m : cnt - 1;
                if (lvl == 0) {
                    int gl = b * NPT_ + child + 2 * pm;
                    clv[r] = c[(size_t)gl * H_ + j];
                    crv[r] = c[(size_t)(gl + 1) * H_ + j];
                } else {
                    int tl = (child - TBASE) + 2 * pm;
                    clv[r] = cl[tl][j];
                    crv[r] = cl[tl + 1][j];
                }
            }

            f32x4 acc[5];
            #pragma unroll
            for (int t = 0; t < 5; ++t) acc[t] = (f32x4){0.f, 0.f, 0.f, 0.f};
            #pragma unroll
            for (int kt = 0; kt < 8; ++kt)
                #pragma unroll
                for (int t = 0; t < 5; ++t)
                    acc[t] = __builtin_amdgcn_mfma_f32_16x16x32_bf16(a[kt], Bf[t][kt], acc[t], 0, 0, 0);

            #pragma unroll
            for (int r = 0; r < 4; ++r) {
                int m = i0 + q * 4 + r;
                if (m < cnt) {
                    int tl = (base - TBASE) + m;
                    float iv = sigmoidf_(acc[0][r] + bi);
                    float ov = sigmoidf_(acc[1][r] + bo);
                    float uv = tanhf_(acc[2][r] + bu);
                    float fl = sigmoidf_(acc[3][r] + bfl);
                    float fr = sigmoidf_(acc[4][r] + bfr);
                    float cv = iv * uv + fl * clv[r] + fr * crv[r];
                    float hv = ov * tanhf_(cv);
                    cl[tl][j] = cv;
                    hl[tl][j] = f2bf(hv);
                }
            }
        }
        __syncthreads();
        child = base; base += cnt; cnt >>= 1;
    }

    if (tid < 128) ev[tid] = bf2f(hl[62][tid]);
    __syncthreads();

    float acc = 0.0f;
    if (tid < 128) {
        acc = b_out[tid];
        for (int k = 0; k < H_; ++k)
            acc += ev[k] * W_out[k * OUT_ + tid];
        red[tid] = acc;
    }
    __syncthreads();
    for (int s = 64; s > 0; s >>= 1) {
        if (tid < s) red[tid] = fmaxf(red[tid], red[tid + s]);
        __syncthreads();
    }
    float mx = red[0];
    __syncthreads();
    if (tid < 128) red[tid] = expf(acc - mx);
    __syncthreads();
    for (int s = 64; s > 0; s >>= 1) {
        if (tid < s) red[tid] += red[tid + s];
        __syncthreads();
    }
    float lse = logf(red[0]);
    if (tid < 128) out[b * OUT_ + tid] = acc - mx - lse;
}

// =====================================================================
extern "C" void kernel_launch(void* const* d_in, const int* in_sizes, int n_in,
                              void* d_out, int out_size, void* d_ws, size_t ws_size,
                              hipStream_t stream) {
    const int*   label = (const int*)d_in[0];
    const float* emb   = (const float*)d_in[1];
    const float* W_iou = (const float*)d_in[2];
    const float* U_iou = (const float*)d_in[3];
    const float* b_iou = (const float*)d_in[4];
    const float* U_f_w = (const float*)d_in[5];
    const float* U_f_b = (const float*)d_in[6];
    const float* W_out = (const float*)d_in[7];
    const float* b_out = (const float*)d_in[8];
    float* outp = (float*)d_out;

    // ws layout: c f32 | h bf16 | Ucat | WT | embb
    float*    c    = (float*)d_ws;
    ushort_t* h    = (ushort_t*)(c + (size_t)N_ * H_);
    ushort_t* Ucat = h + (size_t)N_ * H_;
    ushort_t* WT   = Ucat + 640 * 256;
    ushort_t* embb = WT + 384 * 128;

    prep_fused<<<2000, 256, 0, stream>>>(W_iou, U_iou, U_f_w, emb, WT, Ucat, embb);

    // leaf: 4096 M-tiles of 16; 512 stripes x 2 group-halves; 8 tiles/wave
    leaf_v3<<<dim3(512, 2), 256, 0, stream>>>(label, embb, WT, b_iou, h, c);

    // big levels: cnt = 256,128,64 — B in LDS, M=16/wave, 4 tiles/wave
    int child = 0, node = 512, cnt = 256, lc = 8;
    for (int lvl = 0; lvl < 3; ++lvl) {
        int ntiles  = (B_ * cnt) / 16;
        int stripes = ntiles / 16;          // 4 waves x 4 tiles per block
        level_lds<<<dim3(stripes, 8), 256, 0, stream>>>(
            Ucat, b_iou, U_f_b, h, c, node, child, lc, ntiles);
        child = node; node += cnt; cnt >>= 1; --lc;
    }

    // tail: cnt=32..1 + root, one block per tree
    tail_kernel<<<B_, 512, 0, stream>>>(Ucat, b_iou, U_f_b, h, c, W_out, b_out, outp);
}